// Round 1
// baseline (207.555 us; speedup 1.0000x reference)
//
#include <hip/hip_runtime.h>
#include <stdint.h>

typedef float  f32x4 __attribute__((ext_vector_type(4)));
typedef __bf16 bf16x8 __attribute__((ext_vector_type(8)));
typedef short  s16x8 __attribute__((ext_vector_type(8)));
typedef unsigned short u16;

static __device__ __forceinline__ u16 f2bf(float f) {
  unsigned u = __float_as_uint(f);
  u += 0x7fffu + ((u >> 16) & 1u);
  return (u16)(u >> 16);
}

static __device__ __forceinline__ void async_copy16(void* lds, const void* g) {
  __builtin_amdgcn_global_load_lds(
      (const __attribute__((address_space(1))) unsigned int*)g,
      (__attribute__((address_space(3))) unsigned int*)lds, 16, 0, 0);
}

// ---------------- fp32 -> bf16 convert (weights) ----------------
__global__ __launch_bounds__(256) void cvt_k(const float* __restrict__ in,
                                             u16* __restrict__ out, int n4) {
  int i = blockIdx.x * 256 + threadIdx.x;
  if (i >= n4) return;
  float4 v = reinterpret_cast<const float4*>(in)[i];
  ushort4 o;
  o.x = f2bf(v.x); o.y = f2bf(v.y); o.z = f2bf(v.z); o.w = f2bf(v.w);
  reinterpret_cast<ushort4*>(out)[i] = o;
}

// ---------------- LayerNorm: one block per row, D=1024 ----------------
__global__ __launch_bounds__(256) void ln_k(const float* __restrict__ x,
                                            const float* __restrict__ g,
                                            const float* __restrict__ b,
                                            u16* __restrict__ xn) {
  const int D = 1024;
  const int row = blockIdx.x;
  const int tid = threadIdx.x;
  const float4 v = reinterpret_cast<const float4*>(x + (size_t)row * D)[tid];
  float s  = v.x + v.y + v.z + v.w;
  float s2 = v.x * v.x + v.y * v.y + v.z * v.z + v.w * v.w;
  #pragma unroll
  for (int off = 32; off > 0; off >>= 1) {
    s  += __shfl_down(s, off);
    s2 += __shfl_down(s2, off);
  }
  __shared__ float red[8];
  const int lane = tid & 63, wv = tid >> 6;
  if (lane == 0) { red[wv] = s; red[4 + wv] = s2; }
  __syncthreads();
  s  = red[0] + red[1] + red[2] + red[3];
  s2 = red[4] + red[5] + red[6] + red[7];
  const float mu   = s * (1.0f / D);
  const float var  = s2 * (1.0f / D) - mu * mu;
  const float rstd = rsqrtf(var + 1e-5f);
  const float4 gv = reinterpret_cast<const float4*>(g)[tid];
  const float4 bv = reinterpret_cast<const float4*>(b)[tid];
  ushort4 o;
  o.x = f2bf((v.x - mu) * rstd * gv.x + bv.x);
  o.y = f2bf((v.y - mu) * rstd * gv.y + bv.y);
  o.z = f2bf((v.z - mu) * rstd * gv.z + bv.z);
  o.w = f2bf((v.w - mu) * rstd * gv.w + bv.w);
  reinterpret_cast<ushort4*>(xn + (size_t)row * D)[tid] = o;
}

// ---------------- bf16 GEMM, C = A @ B^T + bias (fp32 out) ----------------
// A: (M,K) row-major bf16. Bm: (N,K) row-major bf16 (i.e. torch Linear weight).
// 128x128 tile, BK=32, 4 waves of 64x64, mfma_f32_16x16x32_bf16.
__global__ __launch_bounds__(256) void gemm_bt_k(const u16* __restrict__ A,
                                                 const u16* __restrict__ Bm,
                                                 const float* __restrict__ bias,
                                                 float* __restrict__ C,
                                                 int M, int N, int K) {
  const int tid  = threadIdx.x;
  const int lane = tid & 63;
  const int wv   = tid >> 6;
  const int ntN  = N >> 7;
  const int mt   = blockIdx.x / ntN;
  const int nt   = blockIdx.x % ntN;
  const int m0 = mt << 7, n0 = nt << 7;

  __shared__ __align__(16) u16 sA[128 * 32];
  __shared__ __align__(16) u16 sB[128 * 32];

  // staging: per wave, 16 rows x 64B per round; 2 rounds each for A and B
  const int srow = wv * 16 + (lane >> 2);
  const int scol = (lane & 3) * 8;
  const u16* gA0 = A  + (size_t)(m0 + srow) * K + scol;
  const u16* gA1 = A  + (size_t)(m0 + 64 + srow) * K + scol;
  const u16* gB0 = Bm + (size_t)(n0 + srow) * K + scol;
  const u16* gB1 = Bm + (size_t)(n0 + 64 + srow) * K + scol;
  u16* lA0 = &sA[(wv * 16) * 32];
  u16* lA1 = &sA[(64 + wv * 16) * 32];
  u16* lB0 = &sB[(wv * 16) * 32];
  u16* lB1 = &sB[(64 + wv * 16) * 32];

  f32x4 acc[4][4];
  #pragma unroll
  for (int i = 0; i < 4; ++i)
    #pragma unroll
    for (int j = 0; j < 4; ++j) acc[i][j] = f32x4{0.f, 0.f, 0.f, 0.f};

  const int wr = (wv >> 1) << 6;   // wave row offset in tile
  const int wc = (wv & 1) << 6;    // wave col offset in tile
  const int fr = lane & 15;
  const int fk = (lane >> 4) << 3;

  for (int k0 = 0; k0 < K; k0 += 32) {
    __syncthreads();
    async_copy16(lA0, gA0 + k0);
    async_copy16(lA1, gA1 + k0);
    async_copy16(lB0, gB0 + k0);
    async_copy16(lB1, gB1 + k0);
    __syncthreads();   // compiler drains vmcnt(0) before s_barrier

    s16x8 af[4], bfr[4];
    #pragma unroll
    for (int i = 0; i < 4; ++i)
      af[i] = *reinterpret_cast<const s16x8*>(&sA[(wr + i * 16 + fr) * 32 + fk]);
    #pragma unroll
    for (int j = 0; j < 4; ++j)
      bfr[j] = *reinterpret_cast<const s16x8*>(&sB[(wc + j * 16 + fr) * 32 + fk]);
    #pragma unroll
    for (int i = 0; i < 4; ++i)
      #pragma unroll
      for (int j = 0; j < 4; ++j)
        acc[i][j] = __builtin_amdgcn_mfma_f32_16x16x32_bf16(
            __builtin_bit_cast(bf16x8, af[i]),
            __builtin_bit_cast(bf16x8, bfr[j]), acc[i][j], 0, 0, 0);
  }

  // epilogue: C/D layout col=lane&15, row=(lane>>4)*4+reg
  const int cr = (lane >> 4) << 2;
  const int cc = lane & 15;
  #pragma unroll
  for (int j = 0; j < 4; ++j) {
    const int col = n0 + wc + j * 16 + cc;
    const float bv = bias[col];
    #pragma unroll
    for (int i = 0; i < 4; ++i) {
      #pragma unroll
      for (int rr = 0; rr < 4; ++rr) {
        const int row = m0 + wr + i * 16 + cr + rr;
        C[(size_t)row * N + col] = acc[i][j][rr] + bv;
      }
    }
  }
}

// ---------------- EMA scan (3-pass chunked), T=128, 32 chunks ----------------
// O[k] = r*O[k-1] + a*(xp[k]-xp[k-1]),  O[-1]=init, xp[-1]=init, r=1-a.
__global__ __launch_bounds__(256) void ema_chunk_k(const float* __restrict__ xp,
                                                   const float* __restrict__ alpha,
                                                   const float* __restrict__ init,
                                                   float* __restrict__ carry) {
  const int Nn = 4096, Dd = 1024, T = 128, nCh = 32;
  int bid = blockIdx.x;
  const int cg = bid & 3;  bid >>= 2;
  const int q  = bid & 31; bid >>= 5;
  const int bb = bid;
  const int c = cg * 256 + threadIdx.x;
  const int h = c >> 7;
  const float a = 1.0f / (1.0f + __expf(-alpha[h]));
  const float r = 1.0f - a;
  const float* px = xp + ((size_t)bb * Nn + (size_t)q * T) * Dd + c;
  float prev = (q == 0) ? init[c] : px[-1024];
  float L = 0.0f;
  #pragma unroll 4
  for (int t = 0; t < T; ++t) {
    float v = px[(size_t)t * Dd];
    L = r * L + a * (v - prev);
    prev = v;
  }
  carry[((size_t)bb * nCh + q) * Dd + c] = L;
}

__global__ __launch_bounds__(256) void ema_carry_k(const float* __restrict__ alpha,
                                                   const float* __restrict__ init,
                                                   float* __restrict__ carry) {
  const int Dd = 1024, nCh = 32;
  const int idx = blockIdx.x * 256 + threadIdx.x;  // 0..B*D-1
  const int c  = idx & (Dd - 1);
  const int bb = idx >> 10;
  const int h = c >> 7;
  const float a = 1.0f / (1.0f + __expf(-alpha[h]));
  const float r = 1.0f - a;
  float rT = r;
  #pragma unroll
  for (int s = 0; s < 7; ++s) rT *= rT;  // r^128
  float cin = init[c];                    // O at chunk-0 start minus 1
  for (int q = 0; q < nCh; ++q) {
    size_t off = ((size_t)bb * nCh + q) * Dd + c;
    float L = carry[off];
    carry[off] = cin;          // incoming O for chunk q
    cin = rT * cin + L;
  }
}

__global__ __launch_bounds__(256) void ema_apply_k(const float* __restrict__ xp,
                                                   const float* __restrict__ alpha,
                                                   const float* __restrict__ init,
                                                   const float* __restrict__ carry,
                                                   u16* __restrict__ ob) {
  const int Nn = 4096, Dd = 1024, T = 128, nCh = 32;
  int bid = blockIdx.x;
  const int cg = bid & 3;  bid >>= 2;
  const int q  = bid & 31; bid >>= 5;
  const int bb = bid;
  const int c = cg * 256 + threadIdx.x;
  const int h = c >> 7;
  const float a = 1.0f / (1.0f + __expf(-alpha[h]));
  const float r = 1.0f - a;
  const float* px = xp + ((size_t)bb * Nn + (size_t)q * T) * Dd + c;
  u16* po = ob + ((size_t)bb * Nn + (size_t)q * T) * Dd + c;
  float O = carry[((size_t)bb * nCh + q) * Dd + c];
  float prev = (q == 0) ? init[c] : px[-1024];
  #pragma unroll 4
  for (int t = 0; t < T; ++t) {
    float v = px[(size_t)t * Dd];
    O = r * O + a * (v - prev);
    prev = v;
    po[(size_t)t * Dd] = f2bf(O);
  }
}

extern "C" void kernel_launch(void* const* d_in, const int* in_sizes, int n_in,
                              void* d_out, int out_size, void* d_ws, size_t ws_size,
                              hipStream_t stream) {
  const float* x     = (const float*)d_in[0];
  const float* ln_g  = (const float*)d_in[1];
  const float* ln_b  = (const float*)d_in[2];
  const float* w_in  = (const float*)d_in[3];
  const float* b_in  = (const float*)d_in[4];
  const float* init  = (const float*)d_in[5];
  const float* alpha = (const float*)d_in[6];
  const float* w_out = (const float*)d_in[7];
  const float* b_out = (const float*)d_in[8];
  float* out = (float*)d_out;

  const int B = 4, N = 4096, D = 1024;
  const int M = B * N;  // 16384

  char* p = (char*)d_ws;
  u16*   xn = (u16*)p;   p += (size_t)M * D * sizeof(u16);    // 32 MB  LN output bf16
  u16*   wi = (u16*)p;   p += (size_t)D * D * sizeof(u16);    // 2 MB   w_in bf16
  u16*   wo = (u16*)p;   p += (size_t)D * D * sizeof(u16);    // 2 MB   w_out bf16
  float* xp = (float*)p; p += (size_t)M * D * sizeof(float);  // 64 MB  project_in out
  float* cr = (float*)p; p += (size_t)B * 32 * D * sizeof(float); // 512 KB carries
  u16*   ob = (u16*)p;                                         // 32 MB  EMA out bf16

  const int n4 = D * D / 4;
  cvt_k<<<dim3((n4 + 255) / 256), dim3(256), 0, stream>>>(w_in, wi, n4);
  cvt_k<<<dim3((n4 + 255) / 256), dim3(256), 0, stream>>>(w_out, wo, n4);
  ln_k<<<dim3(M), dim3(256), 0, stream>>>(x, ln_g, ln_b, xn);
  gemm_bt_k<<<dim3((M / 128) * (D / 128)), dim3(256), 0, stream>>>(xn, wi, b_in, xp, M, D, D);
  ema_chunk_k<<<dim3(B * 32 * 4), dim3(256), 0, stream>>>(xp, alpha, init, cr);
  ema_carry_k<<<dim3(B * D / 256), dim3(256), 0, stream>>>(alpha, init, cr);
  ema_apply_k<<<dim3(B * 32 * 4), dim3(256), 0, stream>>>(xp, alpha, init, cr, ob);
  gemm_bt_k<<<dim3((M / 128) * (D / 128)), dim3(256), 0, stream>>>(ob, wo, b_out, out, M, D, D);
}

// Round 2
// 155.005 us; speedup vs baseline: 1.3390x; 1.3390x over previous
//
#include <hip/hip_runtime.h>
#include <stdint.h>

typedef float  f32x4 __attribute__((ext_vector_type(4)));
typedef __bf16 bf16x8 __attribute__((ext_vector_type(8)));
typedef short  s16x8 __attribute__((ext_vector_type(8)));
typedef unsigned short u16;

static __device__ __forceinline__ u16 f2bf(float f) {
  unsigned u = __float_as_uint(f);
  u += 0x7fffu + ((u >> 16) & 1u);
  return (u16)(u >> 16);
}
static __device__ __forceinline__ float bf2f(u16 u) {
  return __uint_as_float(((unsigned)u) << 16);
}

static __device__ __forceinline__ void async_copy16(void* lds, const void* g) {
  __builtin_amdgcn_global_load_lds(
      (const __attribute__((address_space(1))) unsigned int*)g,
      (__attribute__((address_space(3))) unsigned int*)lds, 16, 0, 0);
}

// ---------------- fp32 -> bf16 convert (weights) ----------------
__global__ __launch_bounds__(256) void cvt_k(const float* __restrict__ in,
                                             u16* __restrict__ out, int n4) {
  int i = blockIdx.x * 256 + threadIdx.x;
  if (i >= n4) return;
  float4 v = reinterpret_cast<const float4*>(in)[i];
  ushort4 o;
  o.x = f2bf(v.x); o.y = f2bf(v.y); o.z = f2bf(v.z); o.w = f2bf(v.w);
  reinterpret_cast<ushort4*>(out)[i] = o;
}

// ---------------- LayerNorm: one block per row, D=1024 ----------------
__global__ __launch_bounds__(256) void ln_k(const float* __restrict__ x,
                                            const float* __restrict__ g,
                                            const float* __restrict__ b,
                                            u16* __restrict__ xn) {
  const int D = 1024;
  const int row = blockIdx.x;
  const int tid = threadIdx.x;
  const float4 v = reinterpret_cast<const float4*>(x + (size_t)row * D)[tid];
  float s  = v.x + v.y + v.z + v.w;
  float s2 = v.x * v.x + v.y * v.y + v.z * v.z + v.w * v.w;
  #pragma unroll
  for (int off = 32; off > 0; off >>= 1) {
    s  += __shfl_down(s, off);
    s2 += __shfl_down(s2, off);
  }
  __shared__ float red[8];
  const int lane = tid & 63, wv = tid >> 6;
  if (lane == 0) { red[wv] = s; red[4 + wv] = s2; }
  __syncthreads();
  s  = red[0] + red[1] + red[2] + red[3];
  s2 = red[4] + red[5] + red[6] + red[7];
  const float mu   = s * (1.0f / D);
  const float var  = s2 * (1.0f / D) - mu * mu;
  const float rstd = rsqrtf(var + 1e-5f);
  const float4 gv = reinterpret_cast<const float4*>(g)[tid];
  const float4 bv = reinterpret_cast<const float4*>(b)[tid];
  ushort4 o;
  o.x = f2bf((v.x - mu) * rstd * gv.x + bv.x);
  o.y = f2bf((v.y - mu) * rstd * gv.y + bv.y);
  o.z = f2bf((v.z - mu) * rstd * gv.z + bv.z);
  o.w = f2bf((v.w - mu) * rstd * gv.w + bv.w);
  reinterpret_cast<ushort4*>(xn + (size_t)row * D)[tid] = o;
}

// ---------------- bf16 GEMM, C = A @ B^T + bias ----------------
// 128x128 tile, BK=64, double-buffered LDS, 2-phase pipeline,
// XOR-swizzled LDS (linear dest + pre-swizzled global src + swizzled read),
// XCD-bijective block swizzle. 4 waves of 64x64, mfma_f32_16x16x32_bf16.
template<int OUT_BF16>
__global__ __launch_bounds__(256) void gemm2_k(const u16* __restrict__ A,
                                               const u16* __restrict__ Bm,
                                               const float* __restrict__ bias,
                                               void* __restrict__ Cv,
                                               int M, int N, int K) {
  const int tid  = threadIdx.x;
  const int lane = tid & 63;
  const int wv   = tid >> 6;
  const int ntN  = N >> 7;
  const int nwg  = (M >> 7) * ntN;
  // XCD-aware bijective swizzle (nwg % 8 == 0): 8 consecutive nt-blocks
  // (sharing an A panel) land on the same XCD's L2.
  const int bid  = blockIdx.x;
  const int wgid = (bid & 7) * (nwg >> 3) + (bid >> 3);
  const int mt = wgid / ntN, nt = wgid % ntN;
  const int m0 = mt << 7, n0 = nt << 7;

  __shared__ __align__(16) u16 sA[2][128 * 64];
  __shared__ __align__(16) u16 sB[2][128 * 64];

  // staging: thread t -> row = t>>3 (+32 per round), 16B chunk = t&7.
  // global source is inverse-swizzled: LDS slot (row,c) holds global chunk c^(row&7).
  const int trow = tid >> 3;
  const int tch  = tid & 7;
  const int csw  = (tch ^ (trow & 7)) << 3;            // element offset in row
  const u16* gA = A  + (size_t)(m0 + trow) * K + csw;
  const u16* gB = Bm + (size_t)(n0 + trow) * K + csw;
  const int lofs = trow * 64 + (tch << 3);             // linear LDS (u16 units)

  f32x4 acc[4][4];
  #pragma unroll
  for (int i = 0; i < 4; ++i)
    #pragma unroll
    for (int j = 0; j < 4; ++j) acc[i][j] = f32x4{0.f, 0.f, 0.f, 0.f};

  const int wr  = (wv >> 1) << 6;
  const int wc  = (wv & 1) << 6;
  const int fr  = lane & 15;
  const int fkc = lane >> 4;     // 16B chunk within a 32-elem k-slice
  const int sx  = fr & 7;        // read-side XOR key ((row&7) == fr&7 here)

  const int nk = K >> 6;
  int buf = 0;

  // prologue
  #pragma unroll
  for (int r = 0; r < 4; ++r) {
    async_copy16(&sA[0][lofs + r * 2048], gA + (size_t)r * 32 * K);
    async_copy16(&sB[0][lofs + r * 2048], gB + (size_t)r * 32 * K);
  }
  __syncthreads();

  for (int t = 0; t < nk; ++t) {
    if (t + 1 < nk) {
      const size_t ko = (size_t)(t + 1) << 6;
      #pragma unroll
      for (int r = 0; r < 4; ++r) {
        async_copy16(&sA[buf ^ 1][lofs + r * 2048], gA + ko + (size_t)r * 32 * K);
        async_copy16(&sB[buf ^ 1][lofs + r * 2048], gB + ko + (size_t)r * 32 * K);
      }
    }
    const u16* bA = sA[buf];
    const u16* bB = sB[buf];
    #pragma unroll
    for (int s = 0; s < 2; ++s) {
      const int ch = ((((s << 2) + fkc) ^ sx) << 3);   // swizzled element offset
      s16x8 af[4], bfr[4];
      #pragma unroll
      for (int i = 0; i < 4; ++i)
        af[i] = *reinterpret_cast<const s16x8*>(&bA[(wr + i * 16 + fr) * 64 + ch]);
      #pragma unroll
      for (int j = 0; j < 4; ++j)
        bfr[j] = *reinterpret_cast<const s16x8*>(&bB[(wc + j * 16 + fr) * 64 + ch]);
      #pragma unroll
      for (int i = 0; i < 4; ++i)
        #pragma unroll
        for (int j = 0; j < 4; ++j)
          acc[i][j] = __builtin_amdgcn_mfma_f32_16x16x32_bf16(
              __builtin_bit_cast(bf16x8, af[i]),
              __builtin_bit_cast(bf16x8, bfr[j]), acc[i][j], 0, 0, 0);
    }
    __syncthreads();   // drains vmcnt(0): next tile staged, this buf free to reuse
    buf ^= 1;
  }

  // epilogue: C/D layout col=lane&15, row=(lane>>4)*4+reg
  const int cr = (lane >> 4) << 2;
  const int cc = lane & 15;
  #pragma unroll
  for (int j = 0; j < 4; ++j) {
    const int col = n0 + wc + j * 16 + cc;
    const float bv = bias[col];
    #pragma unroll
    for (int i = 0; i < 4; ++i) {
      #pragma unroll
      for (int rr = 0; rr < 4; ++rr) {
        const int row = m0 + wr + i * 16 + cr + rr;
        const float val = acc[i][j][rr] + bv;
        if (OUT_BF16) ((u16*)Cv)[(size_t)row * N + col] = f2bf(val);
        else          ((float*)Cv)[(size_t)row * N + col] = val;
      }
    }
  }
}

// ---------------- EMA scan (3-pass chunked), T=128, 32 chunks ----------------
// O[k] = r*O[k-1] + a*(xp[k]-xp[k-1]),  O[-1]=init, xp[-1]=init, r=1-a.
// xp is bf16; each thread handles 2 adjacent channels (4B loads).
__global__ __launch_bounds__(256) void ema_chunk_k(const u16* __restrict__ xp,
                                                   const float* __restrict__ alpha,
                                                   const float* __restrict__ init,
                                                   float* __restrict__ carry) {
  const int Nn = 4096, Dd = 1024, T = 128, nCh = 32;
  int bid = blockIdx.x;
  const int cg = bid & 1;  bid >>= 1;
  const int q  = bid & 31; bid >>= 5;
  const int bb = bid;
  const int c = cg * 512 + threadIdx.x * 2;
  const int h = c >> 7;
  const float a = 1.0f / (1.0f + __expf(-alpha[h]));
  const float r = 1.0f - a;
  const u16* px = xp + ((size_t)bb * Nn + (size_t)q * T) * Dd + c;
  float p0, p1;
  if (q == 0) { p0 = init[c]; p1 = init[c + 1]; }
  else { ushort2 pv = *(const ushort2*)(px - Dd); p0 = bf2f(pv.x); p1 = bf2f(pv.y); }
  float L0 = 0.f, L1 = 0.f;
  #pragma unroll 4
  for (int t = 0; t < T; ++t) {
    ushort2 v = *(const ushort2*)(px + (size_t)t * Dd);
    float v0 = bf2f(v.x), v1 = bf2f(v.y);
    L0 = r * L0 + a * (v0 - p0);
    L1 = r * L1 + a * (v1 - p1);
    p0 = v0; p1 = v1;
  }
  *(float2*)(carry + ((size_t)bb * nCh + q) * Dd + c) = make_float2(L0, L1);
}

__global__ __launch_bounds__(256) void ema_carry_k(const float* __restrict__ alpha,
                                                   const float* __restrict__ init,
                                                   float* __restrict__ carry) {
  const int Dd = 1024, nCh = 32;
  const int idx = blockIdx.x * 256 + threadIdx.x;  // 0..B*D-1
  const int c  = idx & (Dd - 1);
  const int bb = idx >> 10;
  const int h = c >> 7;
  const float a = 1.0f / (1.0f + __expf(-alpha[h]));
  const float r = 1.0f - a;
  float rT = r;
  #pragma unroll
  for (int s = 0; s < 7; ++s) rT *= rT;  // r^128
  float L[32];
  #pragma unroll
  for (int q = 0; q < nCh; ++q)
    L[q] = carry[((size_t)bb * nCh + q) * Dd + c];
  float cin = init[c];
  #pragma unroll
  for (int q = 0; q < nCh; ++q) {
    carry[((size_t)bb * nCh + q) * Dd + c] = cin;  // incoming O for chunk q
    cin = rT * cin + L[q];
  }
}

__global__ __launch_bounds__(256) void ema_apply_k(const u16* __restrict__ xp,
                                                   const float* __restrict__ alpha,
                                                   const float* __restrict__ init,
                                                   const float* __restrict__ carry,
                                                   u16* __restrict__ ob) {
  const int Nn = 4096, Dd = 1024, T = 128, nCh = 32;
  int bid = blockIdx.x;
  const int cg = bid & 1;  bid >>= 1;
  const int q  = bid & 31; bid >>= 5;
  const int bb = bid;
  const int c = cg * 512 + threadIdx.x * 2;
  const int h = c >> 7;
  const float a = 1.0f / (1.0f + __expf(-alpha[h]));
  const float r = 1.0f - a;
  const u16* px = xp + ((size_t)bb * Nn + (size_t)q * T) * Dd + c;
  u16* po = ob + ((size_t)bb * Nn + (size_t)q * T) * Dd + c;
  float2 Oin = *(const float2*)(carry + ((size_t)bb * nCh + q) * Dd + c);
  float O0 = Oin.x, O1 = Oin.y;
  float p0, p1;
  if (q == 0) { p0 = init[c]; p1 = init[c + 1]; }
  else { ushort2 pv = *(const ushort2*)(px - Dd); p0 = bf2f(pv.x); p1 = bf2f(pv.y); }
  #pragma unroll 4
  for (int t = 0; t < T; ++t) {
    ushort2 v = *(const ushort2*)(px + (size_t)t * Dd);
    float v0 = bf2f(v.x), v1 = bf2f(v.y);
    O0 = r * O0 + a * (v0 - p0);
    O1 = r * O1 + a * (v1 - p1);
    p0 = v0; p1 = v1;
    ushort2 o; o.x = f2bf(O0); o.y = f2bf(O1);
    *(ushort2*)(po + (size_t)t * Dd) = o;
  }
}

extern "C" void kernel_launch(void* const* d_in, const int* in_sizes, int n_in,
                              void* d_out, int out_size, void* d_ws, size_t ws_size,
                              hipStream_t stream) {
  const float* x     = (const float*)d_in[0];
  const float* ln_g  = (const float*)d_in[1];
  const float* ln_b  = (const float*)d_in[2];
  const float* w_in  = (const float*)d_in[3];
  const float* b_in  = (const float*)d_in[4];
  const float* init  = (const float*)d_in[5];
  const float* alpha = (const float*)d_in[6];
  const float* w_out = (const float*)d_in[7];
  const float* b_out = (const float*)d_in[8];
  float* out = (float*)d_out;

  const int B = 4, N = 4096, D = 1024;
  const int M = B * N;  // 16384

  char* p = (char*)d_ws;
  u16*   xn  = (u16*)p; p += (size_t)M * D * sizeof(u16);      // 32 MB  LN output bf16
  u16*   wi  = (u16*)p; p += (size_t)D * D * sizeof(u16);      // 2 MB   w_in bf16
  u16*   wo  = (u16*)p; p += (size_t)D * D * sizeof(u16);      // 2 MB   w_out bf16
  u16*   xpb = (u16*)p; p += (size_t)M * D * sizeof(u16);      // 32 MB  project_in out bf16
  float* cr  = (float*)p; p += (size_t)B * 32 * D * sizeof(float); // 512 KB carries
  u16*   ob  = (u16*)p;                                         // 32 MB  EMA out bf16

  const int n4 = D * D / 4;
  cvt_k<<<dim3((n4 + 255) / 256), dim3(256), 0, stream>>>(w_in, wi, n4);
  cvt_k<<<dim3((n4 + 255) / 256), dim3(256), 0, stream>>>(w_out, wo, n4);
  ln_k<<<dim3(M), dim3(256), 0, stream>>>(x, ln_g, ln_b, xn);
  gemm2_k<1><<<dim3((M / 128) * (D / 128)), dim3(256), 0, stream>>>(xn, wi, b_in, xpb, M, D, D);
  ema_chunk_k<<<dim3(B * 32 * 2), dim3(256), 0, stream>>>(xpb, alpha, init, cr);
  ema_carry_k<<<dim3(B * D / 256), dim3(256), 0, stream>>>(alpha, init, cr);
  ema_apply_k<<<dim3(B * 32 * 2), dim3(256), 0, stream>>>(xpb, alpha, init, cr, ob);
  gemm2_k<0><<<dim3((M / 128) * (D / 128)), dim3(256), 0, stream>>>(ob, wo, b_out, out, M, D, D);
}

// Round 3
// 153.834 us; speedup vs baseline: 1.3492x; 1.0076x over previous
//
#include <hip/hip_runtime.h>
#include <stdint.h>

typedef float  f32x4 __attribute__((ext_vector_type(4)));
typedef __bf16 bf16x8 __attribute__((ext_vector_type(8)));
typedef short  s16x8 __attribute__((ext_vector_type(8)));
typedef unsigned short u16;

static __device__ __forceinline__ u16 f2bf(float f) {
  unsigned u = __float_as_uint(f);
  u += 0x7fffu + ((u >> 16) & 1u);
  return (u16)(u >> 16);
}
static __device__ __forceinline__ float bf2f(u16 u) {
  return __uint_as_float(((unsigned)u) << 16);
}

static __device__ __forceinline__ void async_copy16(void* lds, const void* g) {
  __builtin_amdgcn_global_load_lds(
      (const __attribute__((address_space(1))) unsigned int*)g,
      (__attribute__((address_space(3))) unsigned int*)lds, 16, 0, 0);
}

// ---------------- fp32 -> bf16 convert (weights) ----------------
__global__ __launch_bounds__(256) void cvt_k(const float* __restrict__ in,
                                             u16* __restrict__ out, int n4) {
  int i = blockIdx.x * 256 + threadIdx.x;
  if (i >= n4) return;
  float4 v = reinterpret_cast<const float4*>(in)[i];
  ushort4 o;
  o.x = f2bf(v.x); o.y = f2bf(v.y); o.z = f2bf(v.z); o.w = f2bf(v.w);
  reinterpret_cast<ushort4*>(out)[i] = o;
}

// ---------------- LayerNorm: one block per row, D=1024 ----------------
__global__ __launch_bounds__(256) void ln_k(const float* __restrict__ x,
                                            const float* __restrict__ g,
                                            const float* __restrict__ b,
                                            u16* __restrict__ xn) {
  const int D = 1024;
  const int row = blockIdx.x;
  const int tid = threadIdx.x;
  const float4 v = reinterpret_cast<const float4*>(x + (size_t)row * D)[tid];
  float s  = v.x + v.y + v.z + v.w;
  float s2 = v.x * v.x + v.y * v.y + v.z * v.z + v.w * v.w;
  #pragma unroll
  for (int off = 32; off > 0; off >>= 1) {
    s  += __shfl_down(s, off);
    s2 += __shfl_down(s2, off);
  }
  __shared__ float red[8];
  const int lane = tid & 63, wv = tid >> 6;
  if (lane == 0) { red[wv] = s; red[4 + wv] = s2; }
  __syncthreads();
  s  = red[0] + red[1] + red[2] + red[3];
  s2 = red[4] + red[5] + red[6] + red[7];
  const float mu   = s * (1.0f / D);
  const float var  = s2 * (1.0f / D) - mu * mu;
  const float rstd = rsqrtf(var + 1e-5f);
  const float4 gv = reinterpret_cast<const float4*>(g)[tid];
  const float4 bv = reinterpret_cast<const float4*>(b)[tid];
  ushort4 o;
  o.x = f2bf((v.x - mu) * rstd * gv.x + bv.x);
  o.y = f2bf((v.y - mu) * rstd * gv.y + bv.y);
  o.z = f2bf((v.z - mu) * rstd * gv.z + bv.z);
  o.w = f2bf((v.w - mu) * rstd * gv.w + bv.w);
  reinterpret_cast<ushort4*>(xn + (size_t)row * D)[tid] = o;
}

// ---------------- bf16 GEMM, C = A @ B^T + bias: 256^2 8-phase ----------------
// BM=BN=256, BK=64, 512 threads (8 waves, 2Mx4N), double-buffered 128KiB LDS,
// 4 phases/K-tile, raw s_barrier, one vmcnt(0) per K-tile boundary, setprio
// around MFMA clusters, XOR-swizzled LDS, XCD-bijective block swizzle.
static __device__ __forceinline__ s16x8 ldfrag(const u16* b, int row, int ks,
                                               int fkc, int sx) {
  return *reinterpret_cast<const s16x8*>(
      &b[row * 64 + ((((ks << 2) + fkc) ^ sx) << 3)]);
}

template<int OUT_BF16>
__global__ __launch_bounds__(512, 2) void gemm8_k(const u16* __restrict__ A,
                                                  const u16* __restrict__ Bm,
                                                  const float* __restrict__ bias,
                                                  void* __restrict__ Cv,
                                                  int M, int N, int K) {
  const int tid  = threadIdx.x;
  const int lane = tid & 63;
  const int wv   = tid >> 6;      // 0..7
  const int wrr  = wv >> 2;       // 0..1  (wave row)
  const int wcc  = wv & 3;        // 0..3  (wave col)
  const int ntN  = N >> 8;
  const int nwg  = (M >> 8) * ntN;
  const int bid  = blockIdx.x;
  const int wgid = (bid & 7) * (nwg >> 3) + (bid >> 3);   // nwg % 8 == 0
  const int mt = wgid / ntN, nt = wgid % ntN;
  const int m0 = mt << 8, n0 = nt << 8;

  __shared__ __align__(16) u16 sA[2][256 * 64];
  __shared__ __align__(16) u16 sB[2][256 * 64];

  // staging: thread t -> row t>>3 (+64/round), 16B chunk t&7; LDS dest linear
  // (byte off = 16*tid within round), global source inverse-swizzled.
  const int trow = tid >> 3;
  const int tch  = tid & 7;
  const int csw  = (tch ^ (trow & 7)) << 3;
  const u16* gA = A  + (size_t)(m0 + trow) * K + csw;
  const u16* gB = Bm + (size_t)(n0 + trow) * K + csw;
  const int lofs = trow * 64 + (tch << 3);

  f32x4 acc[8][4];
  #pragma unroll
  for (int i = 0; i < 8; ++i)
    #pragma unroll
    for (int j = 0; j < 4; ++j) acc[i][j] = f32x4{0.f, 0.f, 0.f, 0.f};

  const int fr  = lane & 15;
  const int fkc = lane >> 4;
  const int sx  = fr & 7;
  const int abase = wrr << 7;   // wave's A-row base in tile
  const int bbase = wcc << 6;   // wave's B-row (C-col) base in tile

  const int NK = K >> 6;

  // prologue: stage K-tile 0 into buffer 0 (8 rounds)
  #pragma unroll
  for (int r = 0; r < 4; ++r) {
    async_copy16(&sA[0][lofs + r * 4096], gA + (size_t)r * 64 * K);
    async_copy16(&sB[0][lofs + r * 4096], gB + (size_t)r * 64 * K);
  }
  asm volatile("s_waitcnt vmcnt(0)" ::: "memory");
  __builtin_amdgcn_s_barrier();

  s16x8 af[4][2], bfr[2][2];

  for (int kt = 0; kt < NK; ++kt) {
    const int cur = kt & 1;
    const u16* bA = sA[cur];
    const u16* bB = sB[cur];
    u16* nA = sA[cur ^ 1];
    u16* nB = sB[cur ^ 1];
    const bool pf = (kt + 1 < NK);
    const size_t ko = (size_t)(kt + 1) << 6;

    // ---- phase 0: quadrant (mh0, nh0). reads: A(mh0) 8 + B(nh0) 4. stage A r0,r1
    #pragma unroll
    for (int i = 0; i < 4; ++i)
      #pragma unroll
      for (int ks = 0; ks < 2; ++ks)
        af[i][ks] = ldfrag(bA, abase + i * 16 + fr, ks, fkc, sx);
    #pragma unroll
    for (int j = 0; j < 2; ++j)
      #pragma unroll
      for (int ks = 0; ks < 2; ++ks)
        bfr[j][ks] = ldfrag(bB, bbase + j * 16 + fr, ks, fkc, sx);
    if (pf) {
      async_copy16(&nA[lofs], gA + ko);
      async_copy16(&nA[lofs + 4096], gA + ko + (size_t)64 * K);
    }
    __builtin_amdgcn_s_barrier();
    __builtin_amdgcn_s_setprio(1);
    #pragma unroll
    for (int i = 0; i < 4; ++i)
      #pragma unroll
      for (int j = 0; j < 2; ++j)
        #pragma unroll
        for (int ks = 0; ks < 2; ++ks)
          acc[i][j] = __builtin_amdgcn_mfma_f32_16x16x32_bf16(
              __builtin_bit_cast(bf16x8, af[i][ks]),
              __builtin_bit_cast(bf16x8, bfr[j][ks]), acc[i][j], 0, 0, 0);
    __builtin_amdgcn_s_setprio(0);
    __builtin_amdgcn_s_barrier();

    // ---- phase 1: quadrant (mh0, nh1). reads: B(nh1) 4 (reuse A). stage A r2,r3
    #pragma unroll
    for (int j = 0; j < 2; ++j)
      #pragma unroll
      for (int ks = 0; ks < 2; ++ks)
        bfr[j][ks] = ldfrag(bB, bbase + 32 + j * 16 + fr, ks, fkc, sx);
    if (pf) {
      async_copy16(&nA[lofs + 2 * 4096], gA + ko + (size_t)128 * K);
      async_copy16(&nA[lofs + 3 * 4096], gA + ko + (size_t)192 * K);
    }
    __builtin_amdgcn_s_barrier();
    __builtin_amdgcn_s_setprio(1);
    #pragma unroll
    for (int i = 0; i < 4; ++i)
      #pragma unroll
      for (int j = 0; j < 2; ++j)
        #pragma unroll
        for (int ks = 0; ks < 2; ++ks)
          acc[i][2 + j] = __builtin_amdgcn_mfma_f32_16x16x32_bf16(
              __builtin_bit_cast(bf16x8, af[i][ks]),
              __builtin_bit_cast(bf16x8, bfr[j][ks]), acc[i][2 + j], 0, 0, 0);
    __builtin_amdgcn_s_setprio(0);
    __builtin_amdgcn_s_barrier();

    // ---- phase 2: quadrant (mh1, nh1). reads: A(mh1) 8 (reuse B). stage B r0,r1
    #pragma unroll
    for (int i = 0; i < 4; ++i)
      #pragma unroll
      for (int ks = 0; ks < 2; ++ks)
        af[i][ks] = ldfrag(bA, abase + 64 + i * 16 + fr, ks, fkc, sx);
    if (pf) {
      async_copy16(&nB[lofs], gB + ko);
      async_copy16(&nB[lofs + 4096], gB + ko + (size_t)64 * K);
    }
    __builtin_amdgcn_s_barrier();
    __builtin_amdgcn_s_setprio(1);
    #pragma unroll
    for (int i = 0; i < 4; ++i)
      #pragma unroll
      for (int j = 0; j < 2; ++j)
        #pragma unroll
        for (int ks = 0; ks < 2; ++ks)
          acc[4 + i][2 + j] = __builtin_amdgcn_mfma_f32_16x16x32_bf16(
              __builtin_bit_cast(bf16x8, af[i][ks]),
              __builtin_bit_cast(bf16x8, bfr[j][ks]), acc[4 + i][2 + j], 0, 0, 0);
    __builtin_amdgcn_s_setprio(0);
    __builtin_amdgcn_s_barrier();

    // ---- phase 3: quadrant (mh1, nh0). reads: B(nh0) 4 (reuse A). stage B r2,r3
    #pragma unroll
    for (int j = 0; j < 2; ++j)
      #pragma unroll
      for (int ks = 0; ks < 2; ++ks)
        bfr[j][ks] = ldfrag(bB, bbase + j * 16 + fr, ks, fkc, sx);
    if (pf) {
      async_copy16(&nB[lofs + 2 * 4096], gB + ko + (size_t)128 * K);
      async_copy16(&nB[lofs + 3 * 4096], gB + ko + (size_t)192 * K);
    }
    __builtin_amdgcn_s_barrier();
    __builtin_amdgcn_s_setprio(1);
    #pragma unroll
    for (int i = 0; i < 4; ++i)
      #pragma unroll
      for (int j = 0; j < 2; ++j)
        #pragma unroll
        for (int ks = 0; ks < 2; ++ks)
          acc[4 + i][j] = __builtin_amdgcn_mfma_f32_16x16x32_bf16(
              __builtin_bit_cast(bf16x8, af[i][ks]),
              __builtin_bit_cast(bf16x8, bfr[j][ks]), acc[4 + i][j], 0, 0, 0);
    __builtin_amdgcn_s_setprio(0);
    if (pf) asm volatile("s_waitcnt vmcnt(0)" ::: "memory");  // K-tile boundary only
    __builtin_amdgcn_s_barrier();
  }

  // epilogue: C/D layout col=lane&15, row=(lane>>4)*4+reg
  const int cr = (lane >> 4) << 2;
  const int cc = lane & 15;
  #pragma unroll
  for (int nj = 0; nj < 4; ++nj) {
    const int col = n0 + (wcc << 6) + nj * 16 + cc;
    const float bv = bias[col];
    #pragma unroll
    for (int mi = 0; mi < 8; ++mi) {
      #pragma unroll
      for (int rr = 0; rr < 4; ++rr) {
        const int row = m0 + (wrr << 7) + mi * 16 + cr + rr;
        const float val = acc[mi][nj][rr] + bv;
        if (OUT_BF16) ((u16*)Cv)[(size_t)row * N + col] = f2bf(val);
        else          ((float*)Cv)[(size_t)row * N + col] = val;
      }
    }
  }
}

// ---------------- EMA scan (3-pass chunked), T=128, 32 chunks ----------------
// O[k] = r*O[k-1] + a*(xp[k]-xp[k-1]),  O[-1]=init, xp[-1]=init, r=1-a.
__global__ __launch_bounds__(256) void ema_chunk_k(const u16* __restrict__ xp,
                                                   const float* __restrict__ alpha,
                                                   const float* __restrict__ init,
                                                   float* __restrict__ carry) {
  const int Nn = 4096, Dd = 1024, T = 128, nCh = 32;
  int bid = blockIdx.x;
  const int cg = bid & 1;  bid >>= 1;
  const int q  = bid & 31; bid >>= 5;
  const int bb = bid;
  const int c = cg * 512 + threadIdx.x * 2;
  const int h = c >> 7;
  const float a = 1.0f / (1.0f + __expf(-alpha[h]));
  const float r = 1.0f - a;
  const u16* px = xp + ((size_t)bb * Nn + (size_t)q * T) * Dd + c;
  float p0, p1;
  if (q == 0) { p0 = init[c]; p1 = init[c + 1]; }
  else { ushort2 pv = *(const ushort2*)(px - Dd); p0 = bf2f(pv.x); p1 = bf2f(pv.y); }
  float L0 = 0.f, L1 = 0.f;
  #pragma unroll 4
  for (int t = 0; t < T; ++t) {
    ushort2 v = *(const ushort2*)(px + (size_t)t * Dd);
    float v0 = bf2f(v.x), v1 = bf2f(v.y);
    L0 = r * L0 + a * (v0 - p0);
    L1 = r * L1 + a * (v1 - p1);
    p0 = v0; p1 = v1;
  }
  *(float2*)(carry + ((size_t)bb * nCh + q) * Dd + c) = make_float2(L0, L1);
}

__global__ __launch_bounds__(256) void ema_carry_k(const float* __restrict__ alpha,
                                                   const float* __restrict__ init,
                                                   float* __restrict__ carry) {
  const int Dd = 1024, nCh = 32;
  const int idx = blockIdx.x * 256 + threadIdx.x;  // 0..B*D-1
  const int c  = idx & (Dd - 1);
  const int bb = idx >> 10;
  const int h = c >> 7;
  const float a = 1.0f / (1.0f + __expf(-alpha[h]));
  const float r = 1.0f - a;
  float rT = r;
  #pragma unroll
  for (int s = 0; s < 7; ++s) rT *= rT;  // r^128
  float L[32];
  #pragma unroll
  for (int q = 0; q < nCh; ++q)
    L[q] = carry[((size_t)bb * nCh + q) * Dd + c];
  float cin = init[c];
  #pragma unroll
  for (int q = 0; q < nCh; ++q) {
    carry[((size_t)bb * nCh + q) * Dd + c] = cin;  // incoming O for chunk q
    cin = rT * cin + L[q];
  }
}

__global__ __launch_bounds__(256) void ema_apply_k(const u16* __restrict__ xp,
                                                   const float* __restrict__ alpha,
                                                   const float* __restrict__ init,
                                                   const float* __restrict__ carry,
                                                   u16* __restrict__ ob) {
  const int Nn = 4096, Dd = 1024, T = 128, nCh = 32;
  int bid = blockIdx.x;
  const int cg = bid & 1;  bid >>= 1;
  const int q  = bid & 31; bid >>= 5;
  const int bb = bid;
  const int c = cg * 512 + threadIdx.x * 2;
  const int h = c >> 7;
  const float a = 1.0f / (1.0f + __expf(-alpha[h]));
  const float r = 1.0f - a;
  const u16* px = xp + ((size_t)bb * Nn + (size_t)q * T) * Dd + c;
  u16* po = ob + ((size_t)bb * Nn + (size_t)q * T) * Dd + c;
  float2 Oin = *(const float2*)(carry + ((size_t)bb * nCh + q) * Dd + c);
  float O0 = Oin.x, O1 = Oin.y;
  float p0, p1;
  if (q == 0) { p0 = init[c]; p1 = init[c + 1]; }
  else { ushort2 pv = *(const ushort2*)(px - Dd); p0 = bf2f(pv.x); p1 = bf2f(pv.y); }
  #pragma unroll 4
  for (int t = 0; t < T; ++t) {
    ushort2 v = *(const ushort2*)(px + (size_t)t * Dd);
    float v0 = bf2f(v.x), v1 = bf2f(v.y);
    O0 = r * O0 + a * (v0 - p0);
    O1 = r * O1 + a * (v1 - p1);
    p0 = v0; p1 = v1;
    ushort2 o; o.x = f2bf(O0); o.y = f2bf(O1);
    *(ushort2*)(po + (size_t)t * Dd) = o;
  }
}

extern "C" void kernel_launch(void* const* d_in, const int* in_sizes, int n_in,
                              void* d_out, int out_size, void* d_ws, size_t ws_size,
                              hipStream_t stream) {
  const float* x     = (const float*)d_in[0];
  const float* ln_g  = (const float*)d_in[1];
  const float* ln_b  = (const float*)d_in[2];
  const float* w_in  = (const float*)d_in[3];
  const float* b_in  = (const float*)d_in[4];
  const float* init  = (const float*)d_in[5];
  const float* alpha = (const float*)d_in[6];
  const float* w_out = (const float*)d_in[7];
  const float* b_out = (const float*)d_in[8];
  float* out = (float*)d_out;

  const int B = 4, N = 4096, D = 1024;
  const int M = B * N;  // 16384

  char* p = (char*)d_ws;
  u16*   xn  = (u16*)p; p += (size_t)M * D * sizeof(u16);      // 32 MB  LN output bf16
  u16*   wi  = (u16*)p; p += (size_t)D * D * sizeof(u16);      // 2 MB   w_in bf16
  u16*   wo  = (u16*)p; p += (size_t)D * D * sizeof(u16);      // 2 MB   w_out bf16
  u16*   xpb = (u16*)p; p += (size_t)M * D * sizeof(u16);      // 32 MB  project_in out bf16
  float* cr  = (float*)p; p += (size_t)B * 32 * D * sizeof(float); // 512 KB carries
  u16*   ob  = (u16*)p;                                         // 32 MB  EMA out bf16

  const int n4 = D * D / 4;
  cvt_k<<<dim3((n4 + 255) / 256), dim3(256), 0, stream>>>(w_in, wi, n4);
  cvt_k<<<dim3((n4 + 255) / 256), dim3(256), 0, stream>>>(w_out, wo, n4);
  ln_k<<<dim3(M), dim3(256), 0, stream>>>(x, ln_g, ln_b, xn);
  gemm8_k<1><<<dim3((M / 256) * (D / 256)), dim3(512), 0, stream>>>(xn, wi, b_in, xpb, M, D, D);
  ema_chunk_k<<<dim3(B * 32 * 2), dim3(256), 0, stream>>>(xpb, alpha, init, cr);
  ema_carry_k<<<dim3(B * D / 256), dim3(256), 0, stream>>>(alpha, init, cr);
  ema_apply_k<<<dim3(B * 32 * 2), dim3(256), 0, stream>>>(xpb, alpha, init, cr, ob);
  gemm8_k<0><<<dim3((M / 256) * (D / 256)), dim3(512), 0, stream>>>(ob, wo, b_out, out, M, D, D);
}